// Round 5
// baseline (110.199 us; speedup 1.0000x reference)
//
#include <hip/hip_runtime.h>
#include <math.h>

#define NB   32
#define CCH  64
#define HWD  1024
#define CHW  65536     // C*H*W per sample
#define EPSV 1e-5f

typedef __attribute__((ext_vector_type(8))) short bf16x8;
typedef __attribute__((ext_vector_type(4))) float f32x4;

__device__ __forceinline__ unsigned f2b(float x) {
    union { float f; unsigned u; } v; v.f = x;
    return (v.u + 0x7fffu + ((v.u >> 16) & 1u)) >> 16;   // RNE bf16 bits
}
__device__ __forceinline__ float b2f(unsigned short u) {
    union { unsigned u; float f; } v; v.u = ((unsigned)u) << 16;
    return v.f;
}

// ---------------------------------------------------------------------------
// Kernel 1: partial LN stats. grid (chunk=8, which=3, n=32), block 256.
// ---------------------------------------------------------------------------
__global__ __launch_bounds__(256)
void k_stats(const float* __restrict__ q, const float* __restrict__ k,
             const float* __restrict__ v, float* __restrict__ part)
{
    const int chunk = blockIdx.x, which = blockIdx.y, n = blockIdx.z;
    const float* x = (which == 0) ? q : (which == 1 ? k : v);
    const float4* x4 = (const float4*)(x + (size_t)n * CHW) + chunk * 2048;
    float s = 0.f, ss = 0.f;
#pragma unroll
    for (int i = 0; i < 8; ++i) {
        float4 t = x4[threadIdx.x + i * 256];
        s  += t.x + t.y + t.z + t.w;
        ss += t.x * t.x + t.y * t.y + t.z * t.z + t.w * t.w;
    }
    __shared__ float rs[256], rss[256];
    rs[threadIdx.x] = s; rss[threadIdx.x] = ss;
    __syncthreads();
    for (int off = 128; off > 0; off >>= 1) {
        if (threadIdx.x < off) {
            rs[threadIdx.x]  += rs[threadIdx.x + off];
            rss[threadIdx.x] += rss[threadIdx.x + off];
        }
        __syncthreads();
    }
    if (threadIdx.x == 0) {
        const int b = (n * 3 + which) * 8 + chunk;
        part[b * 2 + 0] = rs[0];
        part[b * 2 + 1] = rss[0];
    }
}

// ---------------------------------------------------------------------------
// Kernel 2: finish stats + LayerNorm + 1x1-conv projections.
// grid (pt=16, n=32), block 256. LDS 35 KB -> 4 blocks/CU.
// Outputs: qn fp32 [c][pix];  pqt bf16 [pix][c] (pre-scaled 1/8);
//          pkt bf16 [pix][c];  pvb bf16 [c][pix].
// ---------------------------------------------------------------------------
__global__ __launch_bounds__(256, 4)
void k_proj(const float* __restrict__ q,  const float* __restrict__ k,  const float* __restrict__ v,
            const float* __restrict__ w1, const float* __restrict__ b1,
            const float* __restrict__ w2, const float* __restrict__ b2,
            const float* __restrict__ w3, const float* __restrict__ b3,
            const float* __restrict__ wq, const float* __restrict__ bq,
            const float* __restrict__ wk, const float* __restrict__ bk,
            const float* __restrict__ wv, const float* __restrict__ bv,
            const float* __restrict__ part,
            float* __restrict__ qn, short* __restrict__ pqt,
            short* __restrict__ pkt, short* __restrict__ pvb)
{
    __shared__ float xn[64][68];
    __shared__ float wt[64][68];
    __shared__ float musd[6];
    const int pt = blockIdx.x, n = blockIdx.y;
    const int t = threadIdx.x;

    if (t < 3) {
        float s = 0.f, ss = 0.f;
#pragma unroll
        for (int cidx = 0; cidx < 8; ++cidx) {
            const int b = (n * 3 + t) * 8 + cidx;
            s  += part[b * 2 + 0];
            ss += part[b * 2 + 1];
        }
        const float mu = s * (1.0f / CHW);
        musd[t * 2 + 0] = mu;
        musd[t * 2 + 1] = rsqrtf(ss * (1.0f / CHW) - mu * mu + EPSV);
    }
    __syncthreads();

    const float* src[3]   = {q, k, v};
    const float* lw[3]    = {w1, w2, w3};
    const float* lb[3]    = {b1, b2, b3};
    const float* pw[3]    = {wq, wk, wv};
    const float* pbias[3] = {bq, bk, bv};
    const int p   = t & 63;
    const int ob  = (t >> 6) * 16;
    const int pix = pt * 64 + p;

    for (int tt = 0; tt < 3; ++tt) {
        for (int idx = t; idx < 4096; idx += 256) {
            const int o = idx >> 6, c = idx & 63;
            wt[c][o] = pw[tt][idx];
        }
        const float mu = musd[tt * 2], is = musd[tt * 2 + 1];
        for (int idx = t; idx < 1024; idx += 256) {
            const int c = idx >> 4, p4 = idx & 15;
            const int gi = c * HWD + pt * 64 + p4 * 4;
            float4 xv = *(const float4*)&src[tt][(size_t)n * CHW + gi];
            float4 w4 = *(const float4*)&lw[tt][gi];
            float4 b4 = *(const float4*)&lb[tt][gi];
            float4 r;
            r.x = (xv.x - mu) * is * w4.x + b4.x;
            r.y = (xv.y - mu) * is * w4.y + b4.y;
            r.z = (xv.z - mu) * is * w4.z + b4.z;
            r.w = (xv.w - mu) * is * w4.w + b4.w;
            *(float4*)&xn[c][p4 * 4] = r;
            if (tt == 0) *(float4*)&qn[(size_t)n * CHW + gi] = r;
        }
        __syncthreads();

        float acc[16];
#pragma unroll
        for (int i = 0; i < 16; ++i) acc[i] = pbias[tt][ob + i];
#pragma unroll 4
        for (int c = 0; c < 64; ++c) {
            const float xv = xn[c][p];
#pragma unroll
            for (int o4 = 0; o4 < 4; ++o4) {
                float4 w4 = *(const float4*)&wt[c][ob + o4 * 4];
                acc[o4 * 4 + 0] += w4.x * xv;
                acc[o4 * 4 + 1] += w4.y * xv;
                acc[o4 * 4 + 2] += w4.z * xv;
                acc[o4 * 4 + 3] += w4.w * xv;
            }
        }
        if (tt == 2) {          // V: [c][pix] bf16
#pragma unroll
            for (int i = 0; i < 16; ++i)
                pvb[(size_t)n * CHW + (ob + i) * HWD + pix] = (short)f2b(acc[i]);
        } else {                // Q^T / K^T: [pix][c] bf16 (Q pre-scaled 1/8)
            const float sc = (tt == 0) ? 0.125f : 1.0f;
            unsigned u[8];
#pragma unroll
            for (int i = 0; i < 8; ++i)
                u[i] = (f2b(acc[2 * i + 1] * sc) << 16) | f2b(acc[2 * i] * sc);
            short* dst = (tt == 0) ? pqt : pkt;
            *(uint4*)&dst[(size_t)n * CHW + pix * 64 + ob]     = *(uint4*)&u[0];
            *(uint4*)&dst[(size_t)n * CHW + pix * 64 + ob + 8] = *(uint4*)&u[4];
        }
        __syncthreads();
    }
}

// ---------------------------------------------------------------------------
// Kernel 3 (MFMA): fused attention. One block per (n, 32-column tile).
// 512 threads = 8 waves. Wave w computes S rows i in [w*128, w*128+128).
//   LDS: p_lds  [32 j][1024 i] bf16, row 2048B, XOR-swizzled  (65536 B)
//        q_lds  [32 j][72 c]   bf16                           (4608 B)
//        wredA/wredB [8][32] f32                              (2048 B)
// attn is written from P-LDS as FULL 128B lines (dwordx4, 8 lines/instr) --
// replaces 64 scattered scalar dword stores per thread (the R2-R4 limiter
// hypothesis: 64B-segment partial-line stores cap the write path ~2 TB/s).
// ---------------------------------------------------------------------------
__global__ __launch_bounds__(512, 4)
void k_attn2(const short* __restrict__ pqt, const short* __restrict__ pkt,
             const short* __restrict__ pvb, const float* __restrict__ qn,
             float* __restrict__ xout, float* __restrict__ attn)
{
    __shared__ __align__(16) char smem[65536 + 4608 + 2048];
    short* q_lds = (short*)(smem + 65536);
    float* wredA = (float*)(smem + 65536 + 4608);
    float* wredB = wredA + 256;

    // XCD-bijective swizzle: 1024 wgs = 8 XCDs x 128; 4 consecutive samples/XCD
    const int wg  = blockIdx.x;
    const int xcd = wg & 7, lid = wg >> 3;
    const int n   = xcd * 4 + (lid >> 5);
    const int jb  = lid & 31;                 // 32-col tile index
    const size_t nb = (size_t)n * CHW;
    const int t = threadIdx.x;
    const int w = t >> 6;
    const int l = t & 63;
    const int l15 = l & 15, lg = l >> 4;
    const int ibase = w * 128;

    // ---- stage Q^T tile: q_lds[j][c] (32 j x 64 c, first 256 threads)
    if (t < 256) {
        const int j = t >> 3, c8 = (t & 7) * 8;
        *(bf16x8*)&q_lds[j * 72 + c8] =
            *(const bf16x8*)&pqt[nb + (size_t)(jb * 32 + j) * 64 + c8];
    }
    __syncthreads();

    // ---- phase 1: S = K^T Q   (acc[f][jt], f = i-frag 0..7, jt = j-frag 0..1)
    f32x4 acc[8][2] = {};
#pragma unroll
    for (int ks = 0; ks < 2; ++ks) {
        bf16x8 bqf[2];
#pragma unroll
        for (int jt = 0; jt < 2; ++jt)
            bqf[jt] = *(const bf16x8*)&q_lds[(jt * 16 + l15) * 72 + ks * 32 + lg * 8];
#pragma unroll
        for (int f = 0; f < 8; ++f) {
            const int i = ibase + f * 16 + l15;
            bf16x8 af = *(const bf16x8*)&pkt[nb + (size_t)i * 64 + ks * 32 + lg * 8];
#pragma unroll
            for (int jt = 0; jt < 2; ++jt)
                acc[f][jt] = __builtin_amdgcn_mfma_f32_16x16x32_bf16(
                    af, bqf[jt], acc[f][jt], 0, 0, 0);
        }
    }

    // ---- phase 2: column softmax over i (lane's column j = jt*16 + l15)
    {
        float mx[2];
#pragma unroll
        for (int jt = 0; jt < 2; ++jt) {
            float m = -1e30f;
#pragma unroll
            for (int f = 0; f < 8; ++f)
#pragma unroll
                for (int r = 0; r < 4; ++r) m = fmaxf(m, acc[f][jt][r]);
            m = fmaxf(m, __shfl_xor(m, 16));
            m = fmaxf(m, __shfl_xor(m, 32));
            mx[jt] = m;
        }
        if (l < 16) {
#pragma unroll
            for (int jt = 0; jt < 2; ++jt) wredA[w * 32 + jt * 16 + l] = mx[jt];
        }
    }
    __syncthreads();

    float sm[2];
#pragma unroll
    for (int jt = 0; jt < 2; ++jt) {
        const int j = jt * 16 + l15;
        float cm = wredA[j];
#pragma unroll
        for (int ww = 1; ww < 8; ++ww) cm = fmaxf(cm, wredA[ww * 32 + j]);
        float s = 0.f;
#pragma unroll
        for (int f = 0; f < 8; ++f)
#pragma unroll
            for (int r = 0; r < 4; ++r) {
                float e = __expf(acc[f][jt][r] - cm);
                acc[f][jt][r] = e;
                s += e;
            }
        s += __shfl_xor(s, 16);
        s += __shfl_xor(s, 32);
        sm[jt] = s;
    }
    if (l < 16) {
#pragma unroll
        for (int jt = 0; jt < 2; ++jt) wredB[w * 32 + jt * 16 + l] = sm[jt];
    }
    __syncthreads();

    // ---- phase 3: normalize; P (bf16) -> LDS only (swizzled [j][i])
#pragma unroll
    for (int jt = 0; jt < 2; ++jt) {
        const int j = jt * 16 + l15;
        float s = wredB[j];
#pragma unroll
        for (int ww = 1; ww < 8; ++ww) s += wredB[ww * 32 + j];
        const float inv = 1.0f / s;
#pragma unroll
        for (int f = 0; f < 8; ++f) {
            const int i0 = ibase + f * 16 + lg * 4;
            uint2 pw;
            pw.x = (f2b(acc[f][jt][1] * inv) << 16) | f2b(acc[f][jt][0] * inv);
            pw.y = (f2b(acc[f][jt][3] * inv) << 16) | f2b(acc[f][jt][2] * inv);
            const unsigned byte = (unsigned)j * 2048u + (((unsigned)i0 * 2u) ^ (((unsigned)j & 7u) << 4));
            *(uint2*)(smem + byte) = pw;
        }
    }
    // own-wave LDS writes visible after lgkmcnt; no barrier needed for 3b.

    // ---- phase 3b: coalesced attn write. Per instr: 64 lanes x 16B = 8 full
    // 128B lines. Lane l -> row i = g*8 + (l>>3), cols (l&7)*4 + 0..3.
    {
        float* aout = attn + (size_t)n * HWD * HWD + jb * 32;
        const int rsub = l >> 3;            // row-within-group 0..7
        const int jq   = (l & 7) * 4;       // column quad base
#pragma unroll
        for (int g = 0; g < 16; ++g) {
            const int i = ibase + g * 8 + rsub;
            float f4[4];
#pragma unroll
            for (int rr = 0; rr < 4; ++rr) {
                const int rro = (rr + rsub) & 3;          // bank de-phase
                const unsigned j = (unsigned)(jq + rro);
                const unsigned byte = j * 2048u + (((unsigned)i * 2u) ^ ((j & 7u) << 4));
                f4[rro] = b2f(*(const unsigned short*)(smem + byte));
            }
            *(float4*)&aout[(size_t)i * HWD + jq] = *(float4*)f4;
        }
    }
    __syncthreads();

    // ---- phase 4: out = V * P. Wave w owns c-tile (w&3), j-tile (w>>2).
    f32x4 oacc = {};
    const int cm = w & 3, jn = w >> 2;
    const int j = jn * 16 + l15;
    __builtin_amdgcn_s_setprio(1);
#pragma unroll 4
    for (int ks = 0; ks < 32; ++ks) {
        bf16x8 av = *(const bf16x8*)&pvb[nb + (size_t)(cm * 16 + l15) * HWD + ks * 32 + lg * 8];
        const unsigned ib = (unsigned)(ks * 32 + lg * 8) * 2u;
        bf16x8 bp = *(const bf16x8*)(smem + (unsigned)j * 2048u + (ib ^ (((unsigned)j & 7u) << 4)));
        oacc = __builtin_amdgcn_mfma_f32_16x16x32_bf16(av, bp, oacc, 0, 0, 0);
    }
    __builtin_amdgcn_s_setprio(0);

    // ---- epilogue: x = qn + out
#pragma unroll
    for (int r = 0; r < 4; ++r) {
        const int c = cm * 16 + lg * 4 + r;
        const size_t o = nb + (size_t)c * HWD + jb * 32 + j;
        xout[o] = oacc[r] + qn[o];
    }
}

// ---------------------------------------------------------------------------
extern "C" void kernel_launch(void* const* d_in, const int* in_sizes, int n_in,
                              void* d_out, int out_size, void* d_ws, size_t ws_size,
                              hipStream_t stream)
{
    const float* q  = (const float*)d_in[0];
    const float* k  = (const float*)d_in[1];
    const float* v  = (const float*)d_in[2];
    const float* w1 = (const float*)d_in[3];
    const float* b1 = (const float*)d_in[4];
    const float* w2 = (const float*)d_in[5];
    const float* b2 = (const float*)d_in[6];
    const float* w3 = (const float*)d_in[7];
    const float* b3 = (const float*)d_in[8];
    const float* wq = (const float*)d_in[9];
    const float* bq = (const float*)d_in[10];
    const float* wk = (const float*)d_in[11];
    const float* bk = (const float*)d_in[12];
    const float* wv = (const float*)d_in[13];
    const float* bv = (const float*)d_in[14];

    // ws layout: part fp32 [1536] @0; qn fp32 @4096; pqt/pkt/pvb bf16 after.
    float* ws   = (float*)d_ws;
    float* part = ws;
    float* qn   = ws + 4096;
    short* pqt  = (short*)(qn + 2097152);
    short* pkt  = pqt + 2097152;
    short* pvb  = pkt + 2097152;

    float* xout = (float*)d_out;            // (N, C*H*W)
    float* attn = xout + 2097152;           // (N, HW, HW)

    k_stats<<<dim3(8, 3, 32), 256, 0, stream>>>(q, k, v, part);
    k_proj<<<dim3(16, 32), 256, 0, stream>>>(q, k, v, w1, b1, w2, b2, w3, b3,
                                             wq, bq, wk, bk, wv, bv,
                                             part, qn, pqt, pkt, pvb);
    k_attn2<<<dim3(1024), dim3(512), 0, stream>>>(pqt, pkt, pvb, qn, xout, attn);
}